// Round 8
// baseline (200.640 us; speedup 1.0000x reference)
//
#include <hip/hip_runtime.h>

#define BB 16
#define SS 128
#define DD 256
#define KK 12
#define NN 128
#define WW 116

// One 256-thread block per (b,w); thread (n,h) does d-half h of negative n.
// pred tile staged once in LDS (12 KB), read back at wave-uniform addresses
// (waves 0-1 have h=0, waves 2-3 h=1 -> broadcast, conflict-free).
// R6 lesson: VGPR=32 meant zero loads in flight -> LDS latency serialized
// (VALUBusy 24%). This version batches 12 ds_read_b128 per step into pv[12]
// and reads latent in full-cacheline 64B bursts (lv[4]), with launch_bounds
// relaxed to 4 waves/EU so the compiler has 128 VGPRs to pipeline with.
__global__ __launch_bounds__(256, 4)
void cpc_main(const float* __restrict__ pred,
              const float* __restrict__ latent,
              const int* __restrict__ bidx,
              const int* __restrict__ sidx,
              float* __restrict__ out) {
    const int wg = blockIdx.x;          // b*W + w
    const int b  = wg / WW;
    const int w  = wg - b * WW;
    const int t  = threadIdx.x;
    const int n  = t & (NN - 1);        // negative index
    const int h  = t >> 7;              // d-half: 0 or 1

    __shared__ float predl[KK * DD];    // 12 KB
    __shared__ float sc[KK][NN + 1];    // +1 pad
    __shared__ float posv[KK];

    // ---- stage pred tile: 3 float4 per thread, coalesced ----
    {
        const float4* __restrict__ psrc =
            reinterpret_cast<const float4*>(pred + (size_t)wg * KK * DD);
        float4* pdst = reinterpret_cast<float4*>(predl);
#pragma unroll
        for (int i = 0; i < 3; ++i) pdst[t + i * 256] = psrc[t + i * 256];
    }
    __syncthreads();

    // ---- negative partial scores: thread (n,h), all K, 128 d's ----
    const int i   = (b * NN + n) * WW + w;
    const int seq = (sidx[i] + w) & (SS - 1);
    const int ext = seq + bidx[i] * SS;
    const float* __restrict__ lrow = latent + (size_t)ext * DD + h * (DD / 2);
    const float* __restrict__ prow = predl + h * (DD / 2);   // LDS, wave-uniform

    float acc[KK];
#pragma unroll
    for (int k = 0; k < KK; ++k) acc[k] = 0.f;

    for (int ds = 0; ds < DD / 2; ds += 16) {
        // one full 64B cacheline per thread, 4 loads issued back-to-back
        float4 lv[4];
#pragma unroll
        for (int j = 0; j < 4; ++j)
            lv[j] = *reinterpret_cast<const float4*>(lrow + ds + j * 4);
#pragma unroll
        for (int j = 0; j < 4; ++j) {
            // batch all 12 LDS reads (base + immediate offsets), then FMA
            float4 pv[KK];
#pragma unroll
            for (int k = 0; k < KK; ++k)
                pv[k] = *reinterpret_cast<const float4*>(prow + k * DD + ds + j * 4);
#pragma unroll
            for (int k = 0; k < KK; ++k) {
                acc[k] = fmaf(pv[k].x, lv[j].x, acc[k]);
                acc[k] = fmaf(pv[k].y, lv[j].y, acc[k]);
                acc[k] = fmaf(pv[k].z, lv[j].z, acc[k]);
                acc[k] = fmaf(pv[k].w, lv[j].w, acc[k]);
            }
        }
    }

    constexpr float inv_d = 1.0f / DD;
    if (h == 1) {
#pragma unroll
        for (int k = 0; k < KK; ++k) sc[k][n] = acc[k];
    }
    __syncthreads();
    if (h == 0) {
#pragma unroll
        for (int k = 0; k < KK; ++k) sc[k][n] = (acc[k] + sc[k][n]) * inv_d;
    }

    // ---- positive scores on h=1 threads (overlaps h=0 combine) ----
    if (t >= 128 && t < 224) {
        const int tt = t - 128;
        const int k = tt >> 3, g = tt & 7;
        const float* pr = predl + k * DD + g * 32;          // LDS
        const float* lr = latent + ((size_t)b * SS + (w + k + 1)) * DD + g * 32;
        float s = 0.f;
#pragma unroll
        for (int d = 0; d < 32; d += 4) {
            const float4 pv = *reinterpret_cast<const float4*>(pr + d);
            const float4 lv = *reinterpret_cast<const float4*>(lr + d);
            s = fmaf(pv.x, lv.x, s); s = fmaf(pv.y, lv.y, s);
            s = fmaf(pv.z, lv.z, s); s = fmaf(pv.w, lv.w, s);
        }
        s += __shfl_xor(s, 1);
        s += __shfl_xor(s, 2);
        s += __shfl_xor(s, 4);
        if (g == 0) posv[k] = s * inv_d;
    }
    __syncthreads();

    // ---- logsumexp(129) + argmax==0 per k; 8 lanes per k ----
    if (t < 96) {
        const int k = t >> 3, g = t & 7;
        const float p = posv[k];
        float v[16];
        float m = p;                       // max over all 129 incl. pos
#pragma unroll
        for (int j = 0; j < 16; ++j) {
            v[j] = sc[k][j * 8 + g];
            m = fmaxf(m, v[j]);
        }
        m = fmaxf(m, __shfl_xor(m, 1));
        m = fmaxf(m, __shfl_xor(m, 2));
        m = fmaxf(m, __shfl_xor(m, 4));
        float sum = (g == 0) ? __expf(p - m) : 0.f;   // pos term counted once
#pragma unroll
        for (int j = 0; j < 16; ++j) sum += __expf(v[j] - m);
        sum += __shfl_xor(sum, 1);
        sum += __shfl_xor(sum, 2);
        sum += __shfl_xor(sum, 4);
        if (g == 0) {
            constexpr float inv_bw = 1.0f / (BB * WW);
            const float lse = m + __logf(sum);
            atomicAdd(&out[k], (lse - p) * inv_bw);
            // argmax==0 <=> pos >= max of all 129 (ties pick index 0)
            atomicAdd(&out[KK + k], (p >= m) ? inv_bw : 0.f);
        }
    }
}

extern "C" void kernel_launch(void* const* d_in, const int* in_sizes, int n_in,
                              void* d_out, int out_size, void* d_ws, size_t ws_size,
                              hipStream_t stream) {
    const float* pred   = (const float*)d_in[0];
    const float* latent = (const float*)d_in[1];
    const int*   bidx   = (const int*)d_in[2];
    const int*   sidx   = (const int*)d_in[3];
    float* out = (float*)d_out;
    hipMemsetAsync(out, 0, 2 * KK * sizeof(float), stream);
    cpc_main<<<BB * WW, 256, 0, stream>>>(pred, latent, bidx, sidx, out);
}

// Round 10
// 160.672 us; speedup vs baseline: 1.2488x; 1.2488x over previous
//
#include <hip/hip_runtime.h>
#include <hip/hip_bf16.h>

#define BB 16
#define SS 128
#define DD 256
#define KK 12
#define NN 128
#define WW 116

typedef __attribute__((ext_vector_type(8))) short short8;
typedef __attribute__((ext_vector_type(4))) float f32x4;

// XOR swizzle for [16][512B] bf16 LDS tiles: spreads rows 0-7 across 8
// distinct 16B slots so 16 lanes reading a 512B-strided column are 2-way
// (free) instead of 16-way on banks 0-3 (G4).
__device__ __forceinline__ int swz(int byte_off, int row) {
    return byte_off ^ ((row & 7) << 4);
}

// f32 -> (hi,lo) bf16 split, RNE. dot(x,y) ~= hihi+hilo+lohi, err ~2^-18.
__device__ __forceinline__ void cvt_hilo8(const float4 p, const float4 q,
                                          short8& h, short8& l) {
    float x[8] = {p.x, p.y, p.z, p.w, q.x, q.y, q.z, q.w};
#pragma unroll
    for (int i = 0; i < 8; ++i) {
        __hip_bfloat16 hb = __float2bfloat16(x[i]);
        float hf = __bfloat162float(hb);
        __hip_bfloat16 lb = __float2bfloat16(x[i] - hf);
        h[i] = __builtin_bit_cast(short, hb);
        l[i] = __builtin_bit_cast(short, lb);
    }
}

// One 256-thread block per (b,w). Negative scores via 3-pass bf16-split MFMA:
// wave wv owns negatives [wv*32, wv*32+32) = 2 tiles of 16x16x32 mfma, K=256
// in 8 steps. A (pred, 12 rows pad 16) staged once in LDS bf16 hi/lo,
// XOR-swizzled. B (gathered latent rows) loaded global->reg->cvt per K-step:
// each element used exactly once -> no LDS staging (reuse=0).
__global__ __launch_bounds__(256, 4)
void cpc_main(const float* __restrict__ pred,
              const float* __restrict__ latent,
              const int* __restrict__ bidx,
              const int* __restrict__ sidx,
              float* __restrict__ out) {
    const int wg = blockIdx.x;          // b*W + w
    const int b  = wg / WW;
    const int w  = wg - b * WW;
    const int t  = threadIdx.x;

    __shared__ short Ahi[16 * DD];      // 8 KB, [16][256] bf16 swizzled
    __shared__ short Alo[16 * DD];      // 8 KB
    __shared__ float sc[KK][NN + 1];    // 6.2 KB
    __shared__ float posv[KK];

    const float* __restrict__ pbase = pred + (size_t)wg * KK * DD;

    // ---- stage A = pred tile as bf16 hi/lo ----
    if (t < 96) {                       // 12 rows x 8 segs of 32 els
        const int r = t >> 3, seg = t & 7;
        const float* src = pbase + r * DD + seg * 32;
#pragma unroll
        for (int c = 0; c < 4; ++c) {   // 4 chunks of 8 els (16B bf16)
            float4 p = *reinterpret_cast<const float4*>(src + c * 8);
            float4 q = *reinterpret_cast<const float4*>(src + c * 8 + 4);
            short8 h, l;
            cvt_hilo8(p, q, h, l);
            const int byte = r * 512 + seg * 64 + c * 16;
            *reinterpret_cast<short8*>((char*)Ahi + swz(byte, r)) = h;
            *reinterpret_cast<short8*>((char*)Alo + swz(byte, r)) = l;
        }
    } else if (t < 128) {               // zero pad rows 12..15
        const int u = t - 96;           // 8 threads per row
        const int r = 12 + (u >> 3), seg = u & 7;
        const short8 z = {0, 0, 0, 0, 0, 0, 0, 0};
#pragma unroll
        for (int c = 0; c < 4; ++c) {
            const int byte = r * 512 + seg * 64 + c * 16;
            *reinterpret_cast<short8*>((char*)Ahi + swz(byte, r)) = z;
            *reinterpret_cast<short8*>((char*)Alo + swz(byte, r)) = z;
        }
    }

    // ---- per-lane gather setup (before barrier: overlaps staging) ----
    const int wv   = t >> 6;            // wave 0..3
    const int lane = t & 63;
    const int lr   = lane & 15;         // A row m / B row n-in-tile / D col
    const int lg   = lane >> 4;         // k-group 0..3
    const int n0 = wv * 32 + lr;
    const int n1 = n0 + 16;
    const int i0 = (b * NN + n0) * WW + w;
    const int i1 = (b * NN + n1) * WW + w;
    const int ext0 = ((sidx[i0] + w) & (SS - 1)) + bidx[i0] * SS;
    const int ext1 = ((sidx[i1] + w) & (SS - 1)) + bidx[i1] * SS;
    const float* __restrict__ L0 = latent + (size_t)ext0 * DD + lg * 8;
    const float* __restrict__ L1 = latent + (size_t)ext1 * DD + lg * 8;

    __syncthreads();

    // ---- MFMA K-loop: 8 steps of K=32, 3 passes fused into same acc ----
    f32x4 acc0 = {0.f, 0.f, 0.f, 0.f};
    f32x4 acc1 = {0.f, 0.f, 0.f, 0.f};
    const int abyte = lr * 512 + lg * 16;   // + ks*64
#pragma unroll 2
    for (int ks = 0; ks < 8; ++ks) {
        const short8 ah = *reinterpret_cast<const short8*>(
            (const char*)Ahi + swz(abyte + ks * 64, lr));
        const short8 al = *reinterpret_cast<const short8*>(
            (const char*)Alo + swz(abyte + ks * 64, lr));
        const float4 p0 = *reinterpret_cast<const float4*>(L0 + ks * 32);
        const float4 q0 = *reinterpret_cast<const float4*>(L0 + ks * 32 + 4);
        const float4 p1 = *reinterpret_cast<const float4*>(L1 + ks * 32);
        const float4 q1 = *reinterpret_cast<const float4*>(L1 + ks * 32 + 4);
        short8 bh0, bl0, bh1, bl1;
        cvt_hilo8(p0, q0, bh0, bl0);
        cvt_hilo8(p1, q1, bh1, bl1);
        acc0 = __builtin_amdgcn_mfma_f32_16x16x32_bf16(ah, bh0, acc0, 0, 0, 0);
        acc1 = __builtin_amdgcn_mfma_f32_16x16x32_bf16(ah, bh1, acc1, 0, 0, 0);
        acc0 = __builtin_amdgcn_mfma_f32_16x16x32_bf16(ah, bl0, acc0, 0, 0, 0);
        acc1 = __builtin_amdgcn_mfma_f32_16x16x32_bf16(ah, bl1, acc1, 0, 0, 0);
        acc0 = __builtin_amdgcn_mfma_f32_16x16x32_bf16(al, bh0, acc0, 0, 0, 0);
        acc1 = __builtin_amdgcn_mfma_f32_16x16x32_bf16(al, bh1, acc1, 0, 0, 0);
    }

    // ---- scores -> LDS. D layout: col=lane&15, row=(lane>>4)*4+reg ----
    constexpr float inv_d = 1.0f / DD;
    const int krow = lg * 4;
    if (krow < KK) {                    // lg<3; k rows 12-15 are pad
#pragma unroll
        for (int r = 0; r < 4; ++r) {
            sc[krow + r][n0] = acc0[r] * inv_d;
            sc[krow + r][n1] = acc1[r] * inv_d;
        }
    }

    // ---- positive scores, fp32 VALU (pred from global) ----
    if (t < 96) {
        const int k = t >> 3, g = t & 7;
        const float* pr = pbase + k * DD + g * 32;
        const float* lrow = latent + ((size_t)b * SS + (w + k + 1)) * DD + g * 32;
        float s = 0.f;
#pragma unroll
        for (int d = 0; d < 32; d += 4) {
            const float4 pv = *reinterpret_cast<const float4*>(pr + d);
            const float4 lv = *reinterpret_cast<const float4*>(lrow + d);
            s = fmaf(pv.x, lv.x, s); s = fmaf(pv.y, lv.y, s);
            s = fmaf(pv.z, lv.z, s); s = fmaf(pv.w, lv.w, s);
        }
        s += __shfl_xor(s, 1);
        s += __shfl_xor(s, 2);
        s += __shfl_xor(s, 4);
        if (g == 0) posv[k] = s * inv_d;
    }
    __syncthreads();

    // ---- logsumexp(129) + argmax==0 per k; 8 lanes per k ----
    if (t < 96) {
        const int k = t >> 3, g = t & 7;
        const float p = posv[k];
        float v[16];
        float m = p;
#pragma unroll
        for (int j = 0; j < 16; ++j) {
            v[j] = sc[k][j * 8 + g];
            m = fmaxf(m, v[j]);
        }
        m = fmaxf(m, __shfl_xor(m, 1));
        m = fmaxf(m, __shfl_xor(m, 2));
        m = fmaxf(m, __shfl_xor(m, 4));
        float sum = (g == 0) ? __expf(p - m) : 0.f;
#pragma unroll
        for (int j = 0; j < 16; ++j) sum += __expf(v[j] - m);
        sum += __shfl_xor(sum, 1);
        sum += __shfl_xor(sum, 2);
        sum += __shfl_xor(sum, 4);
        if (g == 0) {
            constexpr float inv_bw = 1.0f / (BB * WW);
            const float lse = m + __logf(sum);
            atomicAdd(&out[k], (lse - p) * inv_bw);
            atomicAdd(&out[KK + k], (p >= m) ? inv_bw : 0.f);
        }
    }
}

extern "C" void kernel_launch(void* const* d_in, const int* in_sizes, int n_in,
                              void* d_out, int out_size, void* d_ws, size_t ws_size,
                              hipStream_t stream) {
    const float* pred   = (const float*)d_in[0];
    const float* latent = (const float*)d_in[1];
    const int*   bidx   = (const int*)d_in[2];
    const int*   sidx   = (const int*)d_in[3];
    float* out = (float*)d_out;
    hipMemsetAsync(out, 0, 2 * KK * sizeof(float), stream);
    cpc_main<<<BB * WW, 256, 0, stream>>>(pred, latent, bidx, sidx, out);
}